// Round 8
// baseline (172.295 us; speedup 1.0000x reference)
//
#include <hip/hip_runtime.h>
#include <hip/hip_cooperative_groups.h>
#include <math.h>

namespace cg = cooperative_groups;

// LDE via MFMA, single cooperative kernel (R8).
// dis^2 = ||x||^2 - 2*(x.dic) + ||dic||^2; GEMM1 (x.dicT, bf16 hi+lo A vs
// bf16 dic) and GEMM2 (e^T.x_hi) on mfma_f32_16x16x32_bf16.
// R8 = R6 tiling (Tc=64: best of 32/64/2048) with the combine fused behind a
// grid.sync() — 512 blocks co-resident (2/CU), phase 2 keeps full 512-block
// combine parallelism (R4's 16-block tail fusion cost ~15 us; this doesn't).

constexpr int Bn = 8, Tn = 2048, Dn = 64, Fn = 128;
constexpr int Tc = 64, DG = 32;
constexpr int NCH = Tn / Tc;        // 32 chunks per (b,dg)
constexpr int NDG = Dn / DG;        // 2
constexpr int XT = 72;              // xsT row stride (ushorts); 144B, 16B-aligned
constexpr int ESS = 72;             // es row stride
constexpr int DS = 136;             // dic_hi row stride
constexpr int RECF = DG * Fn + 2 * DG;   // 4160 floats per (b,dg,chunk) record

typedef short short8 __attribute__((ext_vector_type(8)));
typedef float f32x4 __attribute__((ext_vector_type(4)));

__device__ inline unsigned short f2bf(float v) {          // RNE float->bf16
    union { float f; unsigned u; } c; c.f = v;
    return (unsigned short)((c.u + 0x7FFF + ((c.u >> 16) & 1)) >> 16);
}
__device__ inline float bf2f(unsigned short h) {
    union { unsigned u; float f; } c; c.u = ((unsigned)h) << 16;
    return c.f;
}

__global__ __launch_bounds__(256, 4) void lde_coop(
    const float* __restrict__ x, const float* __restrict__ dic,
    const float* __restrict__ wei, float* __restrict__ ws,
    float* __restrict__ out)
{
    __shared__ unsigned short xsT[Fn * XT];        // x bf16 hi, [f][t]   18.0 KB
    __shared__ unsigned short es[DG * ESS];        // e bf16, [d][t]       4.5 KB
    __shared__ unsigned short dic_hi[DG * DS];     // dic bf16, [d][f]     8.5 KB
    __shared__ float sq[Tc], sp[DG];
    __shared__ float wstat[4][DG], wsum[4][DG];
    __shared__ float s_sc[NCH], s_S, s_pa[Fn];     // phase-2 scratch

    const int tid  = threadIdx.x;
    const int w    = tid >> 6;                     // wave 0..3
    const int lane = tid & 63;
    const int l15  = lane & 15;
    const int quad = lane >> 4;

    // ================= phase 1: per-chunk GEMMs + softmax stats =================
    {
        const int b  = blockIdx.x & 7;             // low bits -> XCD affinity for x[b]
        const int dg = (blockIdx.x >> 3) & (NDG - 1);
        const int tc = blockIdx.x >> 4;
        const int t0 = tc * Tc;
        const int d0 = dg * DG;
        const int tA = w * 16 + l15;               // this lane's GEMM1 A row (local t)

        // ---- x: row loads -> register A-frags (hi+lo); xsT scatter; sq ----
        short8 ahi[4], alo[4];
        {
            const float* xr = x + ((size_t)b * Tn + t0 + tA) * Fn + quad * 8;
            float q = 0.f;
            #pragma unroll
            for (int k = 0; k < 4; ++k) {          // f = k*32 + quad*8 + j
                float4 v0 = *(const float4*)(xr + k * 32);
                float4 v1 = *(const float4*)(xr + k * 32 + 4);
                float vv[8] = {v0.x, v0.y, v0.z, v0.w, v1.x, v1.y, v1.z, v1.w};
                #pragma unroll
                for (int j = 0; j < 8; ++j) {
                    unsigned short h = f2bf(vv[j]);
                    ahi[k][j] = (short)h;
                    alo[k][j] = (short)f2bf(vv[j] - bf2f(h));
                    q += vv[j] * vv[j];
                    xsT[(k * 32 + quad * 8 + j) * XT + tA] = h;   // transpose scatter
                }
            }
            q += __shfl_xor(q, 16);
            q += __shfl_xor(q, 32);
            if (quad == 0) sq[tA] = q;             // exact fp32 ||x_t||^2
        }

        // ---- dic -> bf16 LDS (hi only); sp[d] = ||dic_d||^2 exact ----
        {
            int dl = tid >> 3, fq = (tid & 7) * 16;
            const float4* dp = (const float4*)(dic + (size_t)(d0 + dl) * Fn + fq);
            float p = 0.f;
            #pragma unroll
            for (int i = 0; i < 4; ++i) {
                float4 v = dp[i];
                p += v.x * v.x + v.y * v.y + v.z * v.z + v.w * v.w;
                *(ushort4*)&dic_hi[dl * DS + fq + i * 4] =
                    make_ushort4(f2bf(v.x), f2bf(v.y), f2bf(v.z), f2bf(v.w));
            }
            #pragma unroll
            for (int m = 4; m >= 1; m >>= 1) p += __shfl_xor(p, m);
            if ((tid & 7) == 0) sp[dl] = p;
        }

        // ---- logsumexp(wei), redundantly per wave ----
        float lse;
        {
            float wv = wei[lane];                  // D=64 = wave width
            float m = wv;
            #pragma unroll
            for (int k = 32; k >= 1; k >>= 1) m = fmaxf(m, __shfl_xor(m, k));
            float e = expf(wv - m), s = e;
            #pragma unroll
            for (int k = 32; k >= 1; k >>= 1) s += __shfl_xor(s, k);
            lse = m + logf(s);
        }
        __syncthreads();                           // xsT, dic_hi, sq, sp ready

        // ---- GEMM1: S[t][d] = x . dicT (A regs, B LDS), K=128 ----
        f32x4 acc1[2] = {{0.f, 0.f, 0.f, 0.f}, {0.f, 0.f, 0.f, 0.f}};
        #pragma unroll
        for (int k = 0; k < 4; ++k) {
            #pragma unroll
            for (int nt = 0; nt < 2; ++nt) {
                short8 bhi = *(const short8*)&dic_hi[(nt * 16 + l15) * DS + k * 32 + quad * 8];
                acc1[nt] = __builtin_amdgcn_mfma_f32_16x16x32_bf16(ahi[k], bhi, acc1[nt], 0, 0, 0);
                acc1[nt] = __builtin_amdgcn_mfma_f32_16x16x32_bf16(alo[k], bhi, acc1[nt], 0, 0, 0);
            }
        }

        // ---- logits + chunk softmax (C layout: col=l15 -> d, row=quad*4+r -> t) ----
        float logit[2][4], Mc[2], eloc[2][4];
        #pragma unroll
        for (int nt = 0; nt < 2; ++nt) {
            float lsm = wei[d0 + nt * 16 + l15] - lse;
            #pragma unroll
            for (int r = 0; r < 4; ++r) {
                int tt = w * 16 + quad * 4 + r;
                float s2 = sq[tt] - 2.f * acc1[nt][r] + sp[nt * 16 + l15];
                logit[nt][r] = -sqrtf(fmaxf(s2, 0.f)) * lsm;
            }
            float m = fmaxf(fmaxf(logit[nt][0], logit[nt][1]),
                            fmaxf(logit[nt][2], logit[nt][3]));
            m = fmaxf(m, __shfl_xor(m, 16));
            m = fmaxf(m, __shfl_xor(m, 32));
            if (quad == 0) wstat[w][nt * 16 + l15] = m;
        }
        __syncthreads();
        #pragma unroll
        for (int nt = 0; nt < 2; ++nt) {
            int dd = nt * 16 + l15;
            Mc[nt] = fmaxf(fmaxf(wstat[0][dd], wstat[1][dd]),
                           fmaxf(wstat[2][dd], wstat[3][dd]));
            float s = 0.f;
            #pragma unroll
            for (int r = 0; r < 4; ++r) {
                float e = expf(logit[nt][r] - Mc[nt]);
                eloc[nt][r] = e;
                s += e;
            }
            s += __shfl_xor(s, 16);
            s += __shfl_xor(s, 32);
            if (quad == 0) wsum[w][dd] = s;
            #pragma unroll
            for (int r = 0; r < 4; ++r)            // es[d][t] bf16 (GEMM2 A layout)
                es[dd * ESS + w * 16 + quad * 4 + r] = f2bf(eloc[nt][r]);
        }
        __syncthreads();
        float* rec = ws + (size_t)((b * NDG + dg) * NCH + tc) * RECF;
        if (w == 0 && quad == 0) {                 // chunk stats
            rec[DG * Fn + l15]      = Mc[0];
            rec[DG * Fn + 16 + l15] = Mc[1];
            rec[DG * Fn + DG + l15]      = wsum[0][l15] + wsum[1][l15] + wsum[2][l15] + wsum[3][l15];
            rec[DG * Fn + DG + 16 + l15] = wsum[0][16 + l15] + wsum[1][16 + l15]
                                         + wsum[2][16 + l15] + wsum[3][16 + l15];
        }

        // ---- GEMM2: A[d][f] = e^T . x_hi; wave w owns f in [w*32, w*32+32) ----
        f32x4 acc2[2][2] = {{{0.f,0.f,0.f,0.f},{0.f,0.f,0.f,0.f}},
                            {{0.f,0.f,0.f,0.f},{0.f,0.f,0.f,0.f}}};
        const int f0w = w * 32;
        #pragma unroll
        for (int ks = 0; ks < 2; ++ks) {
            short8 af[2];
            #pragma unroll
            for (int mt = 0; mt < 2; ++mt)
                af[mt] = *(const short8*)&es[(mt * 16 + l15) * ESS + ks * 32 + quad * 8];
            #pragma unroll
            for (int nt = 0; nt < 2; ++nt) {
                short8 bfr = *(const short8*)&xsT[(f0w + nt * 16 + l15) * XT + ks * 32 + quad * 8];
                #pragma unroll
                for (int mt = 0; mt < 2; ++mt)
                    acc2[mt][nt] = __builtin_amdgcn_mfma_f32_16x16x32_bf16(af[mt], bfr, acc2[mt][nt], 0, 0, 0);
            }
        }
        #pragma unroll
        for (int mt = 0; mt < 2; ++mt)
            #pragma unroll
            for (int nt = 0; nt < 2; ++nt)
                #pragma unroll
                for (int r = 0; r < 4; ++r)
                    rec[(mt * 16 + quad * 4 + r) * Fn + f0w + nt * 16 + l15] = acc2[mt][nt][r];
    }

    // ================= grid-wide sync, then phase 2: flash-combine =================
    __threadfence();                               // release records device-wide
    cg::this_grid().sync();

    {
        const int b = blockIdx.x & 7;              // 512 blocks = 8 b x 64 d
        const int d = blockIdx.x >> 3;
        const int dg = d >> 5, dl = d & 31;

        const float* base = ws + (size_t)((b * NDG + dg) * NCH) * RECF;

        // ---- M and S across 32 chunks, parallel (lanes 32..63 duplicate) ----
        if (tid < 64) {
            int c = tid & 31;
            float Mc = base[(size_t)c * RECF + DG * Fn + dl];
            float Sc = base[(size_t)c * RECF + DG * Fn + DG + dl];
            float M = Mc;
            #pragma unroll
            for (int m = 32; m >= 1; m >>= 1) M = fmaxf(M, __shfl_xor(M, m));
            float sck = expf(Mc - M);              // A-merge weight
            float S = Sc * sck;                    // Sc multiplies ONLY the S-sum
            #pragma unroll
            for (int m = 32; m >= 1; m >>= 1) S += __shfl_xor(S, m);
            if (tid < 32) s_sc[tid] = sck;
            if (tid == 0) s_S = S * 0.5f;          // 64-lane sum counts each chunk twice
        }
        __syncthreads();

        // ---- A-merge: 256 threads = 128 f x 2 chunk-halves, coalesced loads ----
        const int f = tid & 127, h = tid >> 7;
        float a = 0.f;
        #pragma unroll
        for (int i = 0; i < 16; ++i) {
            int c = h * 16 + i;
            a += base[(size_t)c * RECF + dl * Fn + f] * s_sc[c];
        }
        if (h == 1) s_pa[f] = a;
        __syncthreads();
        if (h == 0) {
            a += s_pa[f];
            float S = s_S;
            out[((size_t)b * Dn + d) * Fn + f] = (a - S * dic[d * Fn + f]) / S;
        }
    }
}

extern "C" void kernel_launch(void* const* d_in, const int* in_sizes, int n_in,
                              void* d_out, int out_size, void* d_ws, size_t ws_size,
                              hipStream_t stream) {
    const float* x   = (const float*)d_in[0];
    const float* dic = (const float*)d_in[1];
    const float* wei = (const float*)d_in[2];
    float* out = (float*)d_out;
    float* ws  = (float*)d_ws;                     // records: 8.52 MB

    void* args[] = {(void*)&x, (void*)&dic, (void*)&wei, (void*)&ws, (void*)&out};
    hipLaunchCooperativeKernel((const void*)lde_coop, dim3(Bn * NDG * NCH),
                               dim3(256), args, 0, stream);
}

// Round 10
// 71.759 us; speedup vs baseline: 2.4010x; 2.4010x over previous
//
#include <hip/hip_runtime.h>
#include <math.h>

// LDE via MFMA, two kernels (R10 = R6 structure + bf16 A-records).
// dis^2 = ||x||^2 - 2*(x.dic) + ||dic||^2; GEMM1 (x.dicT, bf16 hi+lo A vs
// bf16 dic) and GEMM2 (e^T.x_hi) on mfma_f32_16x16x32_bf16.
// Per-chunk max normalization kept (es in (0,1], records O(1)): R9's static
// shift scaled records to ~1e-13 = 0xAA-poison scale and diverged post-timing.
// Tc=64 two-kernel layout is the measured optimum (R6 75.2us; Tc=32 regressed,
// tail-fusion and grid.sync both regressed badly).

constexpr int Bn = 8, Tn = 2048, Dn = 64, Fn = 128;
constexpr int Tc = 64, DG = 32;
constexpr int NCH = Tn / Tc;        // 32 chunks per (b,dg)
constexpr int NDG = Dn / DG;        // 2
constexpr int XT = 72;              // xsT row stride (ushorts); 144B, 16B-aligned
constexpr int ESS = 72;             // es row stride
constexpr int DS = 136;             // dic_hi row stride
constexpr int RECA = DG * Fn;                         // 4096 bf16 A values
constexpr size_t RECB = (size_t)RECA * 2 + 2 * DG * 4;  // 8448 B/record: A + Mc[32] + Sc[32]

typedef short short8 __attribute__((ext_vector_type(8)));
typedef float f32x4 __attribute__((ext_vector_type(4)));

__device__ inline unsigned short f2bf(float v) {          // RNE float->bf16
    union { float f; unsigned u; } c; c.f = v;
    return (unsigned short)((c.u + 0x7FFF + ((c.u >> 16) & 1)) >> 16);
}
__device__ inline float bf2f(unsigned short h) {
    union { unsigned u; float f; } c; c.u = ((unsigned)h) << 16;
    return c.f;
}

__global__ __launch_bounds__(256, 4) void lde_main(
    const float* __restrict__ x, const float* __restrict__ dic,
    const float* __restrict__ wei, char* __restrict__ ws)
{
    const int b  = blockIdx.x & 7;                 // low bits -> XCD affinity for x[b]
    const int dg = (blockIdx.x >> 3) & (NDG - 1);
    const int tc = blockIdx.x >> 4;
    const int t0 = tc * Tc;
    const int d0 = dg * DG;

    __shared__ unsigned short xsT[Fn * XT];        // x bf16 hi, [f][t]   18.0 KB
    __shared__ unsigned short es[DG * ESS];        // e bf16, [d][t]       4.5 KB
    __shared__ unsigned short dic_hi[DG * DS];     // dic bf16, [d][f]     8.5 KB
    __shared__ float sq[Tc], sp[DG];
    __shared__ float wstat[4][DG], wsum[4][DG];

    const int tid  = threadIdx.x;
    const int w    = tid >> 6;                     // wave 0..3
    const int lane = tid & 63;
    const int l15  = lane & 15;
    const int quad = lane >> 4;
    const int tA   = w * 16 + l15;                 // this lane's GEMM1 A row (local t)

    // ---- x: row loads -> register A-frags (hi+lo); xsT scatter; sq ----
    short8 ahi[4], alo[4];
    {
        const float* xr = x + ((size_t)b * Tn + t0 + tA) * Fn + quad * 8;
        float q = 0.f;
        #pragma unroll
        for (int k = 0; k < 4; ++k) {              // f = k*32 + quad*8 + j
            float4 v0 = *(const float4*)(xr + k * 32);
            float4 v1 = *(const float4*)(xr + k * 32 + 4);
            float vv[8] = {v0.x, v0.y, v0.z, v0.w, v1.x, v1.y, v1.z, v1.w};
            #pragma unroll
            for (int j = 0; j < 8; ++j) {
                unsigned short h = f2bf(vv[j]);
                ahi[k][j] = (short)h;
                alo[k][j] = (short)f2bf(vv[j] - bf2f(h));
                q += vv[j] * vv[j];
                xsT[(k * 32 + quad * 8 + j) * XT + tA] = h;   // transpose scatter
            }
        }
        q += __shfl_xor(q, 16);                    // sum the 4 quads of row tA
        q += __shfl_xor(q, 32);
        if (quad == 0) sq[tA] = q;                 // exact fp32 ||x_t||^2
    }

    // ---- dic -> bf16 LDS (hi only); sp[d] = ||dic_d||^2 exact ----
    {
        int dl = tid >> 3, fq = (tid & 7) * 16;    // 8 threads per d, 16 f each
        const float4* dp = (const float4*)(dic + (size_t)(d0 + dl) * Fn + fq);
        float p = 0.f;
        #pragma unroll
        for (int i = 0; i < 4; ++i) {
            float4 v = dp[i];
            p += v.x * v.x + v.y * v.y + v.z * v.z + v.w * v.w;
            *(ushort4*)&dic_hi[dl * DS + fq + i * 4] =
                make_ushort4(f2bf(v.x), f2bf(v.y), f2bf(v.z), f2bf(v.w));
        }
        #pragma unroll
        for (int m = 4; m >= 1; m >>= 1) p += __shfl_xor(p, m);
        if ((tid & 7) == 0) sp[dl] = p;
    }

    // ---- logsumexp(wei), redundantly per wave ----
    float lse;
    {
        float wv = wei[lane];                      // D=64 = wave width
        float m = wv;
        #pragma unroll
        for (int k = 32; k >= 1; k >>= 1) m = fmaxf(m, __shfl_xor(m, k));
        float e = expf(wv - m), s = e;
        #pragma unroll
        for (int k = 32; k >= 1; k >>= 1) s += __shfl_xor(s, k);
        lse = m + logf(s);
    }
    __syncthreads();                               // xsT, dic_hi, sq, sp ready

    // ---- GEMM1: S[t][d] = x . dicT (A regs, B LDS), K=128 ----
    f32x4 acc1[2] = {{0.f, 0.f, 0.f, 0.f}, {0.f, 0.f, 0.f, 0.f}};
    #pragma unroll
    for (int k = 0; k < 4; ++k) {
        #pragma unroll
        for (int nt = 0; nt < 2; ++nt) {
            short8 bhi = *(const short8*)&dic_hi[(nt * 16 + l15) * DS + k * 32 + quad * 8];
            acc1[nt] = __builtin_amdgcn_mfma_f32_16x16x32_bf16(ahi[k], bhi, acc1[nt], 0, 0, 0);
            acc1[nt] = __builtin_amdgcn_mfma_f32_16x16x32_bf16(alo[k], bhi, acc1[nt], 0, 0, 0);
        }
    }

    // ---- logits + chunk softmax (C layout: col=l15 -> d, row=quad*4+r -> t) ----
    float logit[2][4], Mc[2], Sc[2], eloc[2][4];
    #pragma unroll
    for (int nt = 0; nt < 2; ++nt) {
        float lsm = wei[d0 + nt * 16 + l15] - lse;
        #pragma unroll
        for (int r = 0; r < 4; ++r) {
            int tt = w * 16 + quad * 4 + r;
            float s2 = sq[tt] - 2.f * acc1[nt][r] + sp[nt * 16 + l15];
            logit[nt][r] = -sqrtf(fmaxf(s2, 0.f)) * lsm;
        }
        float m = fmaxf(fmaxf(logit[nt][0], logit[nt][1]),
                        fmaxf(logit[nt][2], logit[nt][3]));
        m = fmaxf(m, __shfl_xor(m, 16));
        m = fmaxf(m, __shfl_xor(m, 32));
        if (quad == 0) wstat[w][nt * 16 + l15] = m;
    }
    __syncthreads();
    #pragma unroll
    for (int nt = 0; nt < 2; ++nt) {
        int dd = nt * 16 + l15;
        Mc[nt] = fmaxf(fmaxf(wstat[0][dd], wstat[1][dd]),
                       fmaxf(wstat[2][dd], wstat[3][dd]));
        float s = 0.f;
        #pragma unroll
        for (int r = 0; r < 4; ++r) {
            float e = expf(logit[nt][r] - Mc[nt]);
            eloc[nt][r] = e;
            s += e;
        }
        s += __shfl_xor(s, 16);
        s += __shfl_xor(s, 32);
        if (quad == 0) wsum[w][dd] = s;
        #pragma unroll
        for (int r = 0; r < 4; ++r)                // es[d][t] bf16 (GEMM2 A layout)
            es[dd * ESS + w * 16 + quad * 4 + r] = f2bf(eloc[nt][r]);
    }
    __syncthreads();                               // es + wsum ready

    char* recb = ws + (size_t)((b * NDG + dg) * NCH + tc) * RECB;
    unsigned short* recA = (unsigned short*)recb;
    float* recMS = (float*)(recb + (size_t)RECA * 2);
    #pragma unroll
    for (int nt = 0; nt < 2; ++nt)
        Sc[nt] = wsum[0][nt * 16 + l15] + wsum[1][nt * 16 + l15]
               + wsum[2][nt * 16 + l15] + wsum[3][nt * 16 + l15];
    if (w == 0 && quad == 0) {                     // chunk stats: Mc[32], Sc[32]
        recMS[l15]           = Mc[0];
        recMS[16 + l15]      = Mc[1];
        recMS[DG + l15]      = Sc[0];
        recMS[DG + 16 + l15] = Sc[1];
    }

    // ---- GEMM2: A[d][f] = e^T . x_hi; wave w owns f in [w*32, w*32+32) ----
    f32x4 acc2[2][2] = {{{0.f,0.f,0.f,0.f},{0.f,0.f,0.f,0.f}},
                        {{0.f,0.f,0.f,0.f},{0.f,0.f,0.f,0.f}}};
    const int f0w = w * 32;
    #pragma unroll
    for (int ks = 0; ks < 2; ++ks) {
        short8 af[2];
        #pragma unroll
        for (int mt = 0; mt < 2; ++mt)
            af[mt] = *(const short8*)&es[(mt * 16 + l15) * ESS + ks * 32 + quad * 8];
        #pragma unroll
        for (int nt = 0; nt < 2; ++nt) {
            short8 bfr = *(const short8*)&xsT[(f0w + nt * 16 + l15) * XT + ks * 32 + quad * 8];
            #pragma unroll
            for (int mt = 0; mt < 2; ++mt)
                acc2[mt][nt] = __builtin_amdgcn_mfma_f32_16x16x32_bf16(af[mt], bfr, acc2[mt][nt], 0, 0, 0);
        }
    }
    #pragma unroll
    for (int mt = 0; mt < 2; ++mt)
        #pragma unroll
        for (int nt = 0; nt < 2; ++nt)
            #pragma unroll
            for (int r = 0; r < 4; ++r)
                recA[(mt * 16 + quad * 4 + r) * Fn + f0w + nt * 16 + l15] =
                    f2bf(acc2[mt][nt][r]);         // O(1)-scale values: bf16-safe
}

__global__ __launch_bounds__(256) void lde_combine(
    const char* __restrict__ ws, const float* __restrict__ dic,
    float* __restrict__ out)
{
    const int b = blockIdx.x & 7;
    const int d = blockIdx.x >> 3;
    const int dg = d >> 5, dl = d & 31;
    const int tid = threadIdx.x;

    __shared__ float s_sc[NCH];                    // exp(Mc - M) per chunk
    __shared__ float s_S;
    __shared__ float s_pa[Fn];

    const char* base = ws + (size_t)((b * NDG + dg) * NCH) * RECB;

    // ---- M and S across 32 chunks, parallel (lanes 32..63 duplicate) ----
    if (tid < 64) {
        int c = tid & 31;
        const float* ms = (const float*)(base + (size_t)c * RECB + (size_t)RECA * 2);
        float Mc = ms[dl];
        float Sc = ms[DG + dl];
        float M = Mc;
        #pragma unroll
        for (int m = 32; m >= 1; m >>= 1) M = fmaxf(M, __shfl_xor(M, m));
        float sck = expf(Mc - M);                  // A-merge weight
        float S = Sc * sck;                        // Sc multiplies ONLY the S-sum
        #pragma unroll
        for (int m = 32; m >= 1; m >>= 1) S += __shfl_xor(S, m);
        if (tid < 32) s_sc[tid] = sck;
        if (tid == 0) s_S = S * 0.5f;              // 64-lane sum counts each chunk twice
    }
    __syncthreads();

    // ---- A-merge: 256 threads = 128 f x 2 chunk-halves, coalesced bf16 loads ----
    const int f = tid & 127, h = tid >> 7;
    float a = 0.f;
    #pragma unroll
    for (int i = 0; i < 16; ++i) {
        int c = h * 16 + i;
        const unsigned short* rA = (const unsigned short*)(base + (size_t)c * RECB);
        a += bf2f(rA[dl * Fn + f]) * s_sc[c];
    }
    if (h == 1) s_pa[f] = a;
    __syncthreads();
    if (h == 0) {
        a += s_pa[f];
        float S = s_S;
        out[((size_t)b * Dn + d) * Fn + f] = (a - S * dic[d * Fn + f]) / S;
    }
}

extern "C" void kernel_launch(void* const* d_in, const int* in_sizes, int n_in,
                              void* d_out, int out_size, void* d_ws, size_t ws_size,
                              hipStream_t stream) {
    const float* x   = (const float*)d_in[0];
    const float* dic = (const float*)d_in[1];
    const float* wei = (const float*)d_in[2];
    float* out = (float*)d_out;
    char* ws   = (char*)d_ws;                      // records: 512 * 8448 B = 4.33 MB

    hipLaunchKernelGGL(lde_main, dim3(Bn * NDG * NCH), dim3(256), 0, stream,
                       x, dic, wei, ws);
    hipLaunchKernelGGL(lde_combine, dim3(Bn * Dn), dim3(256), 0, stream,
                       ws, dic, out);
}